// Round 7
// baseline (224.249 us; speedup 1.0000x reference)
//
#include <hip/hip_runtime.h>

// WaveConv3d: B=4, C=32, D=H=W=64, LEVEL=2, m=16.
// Stage 1: s[inp][k][b][c][v16] = (1/8) * WHT3( 2x2x2 sums of 4x4x4 block )
// Stage 2: mixed[k][b][o][v] = sum_i s1*W1 + s2*W2   (per-voxel 32x32 mixing)
// Stage 3: out = (1/8) * invWHT3(mixed) broadcast to 4x4x4 blocks
//
// R6: DIAGNOSTIC ROUND. R0-R5: five structurally different k_fwds (VGPR
// loads scattered/linear, sync gl_lds, persistent dbuf gl_lds w/ counted
// vmcnt) ALL land at 100-105us for 268MB read + 33MB write. Two full-size
// ablation probes run before the unchanged pipeline to split the cost:
//   k_probe_read  = R5 staging loop verbatim, NO compute, NO stores.
//   k_probe_write = k_fwd's exact 8xKS-strided store pattern, zeros.
// Readout: probe_read ~100us -> bare read path is the cap.
//          probe_read ~40us  -> in-loop store/compute coupling is the cap.
//          probe_write >50us -> strided scalar stores are the cap.

#define M3 4096        // 16*16*16 voxels
#define KS 524288      // 4*32*M3  : k-stride in s / mixed
#define IS 4194304     // 8*KS     : input-stride in s
#define NSLAB 16

__global__ __launch_bounds__(512) void k_probe_read(const float* __restrict__ x1,
                                                    const float* __restrict__ x2) {
  const int blk = blockIdx.x;          // 256 blocks: inp*128 + bc
  const int bc  = blk & 127;
  const int inp = blk >> 7;
  const float* __restrict__ X = (inp ? x2 : x1) + (size_t)bc * 262144;

  __shared__ __align__(16) float buf[2][16384];   // 2 x 64 KB

  const int tid  = threadIdx.x;
  const int lane = tid & 63;
  const int wv   = tid >> 6;           // 8 waves

  auto stage = [&](int xsl, int bi) {
#pragma unroll
    for (int r = 0; r < 8; ++r) {
      const int cn = wv * 8 + r;                          // 1KB chunk 0..63
      const int gslot = cn * 64 + (lane ^ ((cn & 3) << 1));   // swizzled src
      __builtin_amdgcn_global_load_lds(
          (const __attribute__((address_space(1))) void*)(
              X + (size_t)xsl * 16384 + (size_t)gslot * 4),
          (__attribute__((address_space(3))) void*)(&buf[bi][cn * 256]),
          16, 0, 0);
    }
  };

  stage(0, 0);
  for (int t = 0; t < NSLAB; ++t) {
    if (t + 1 < NSLAB) {
      stage(t + 1, (t + 1) & 1);
      asm volatile("s_waitcnt vmcnt(8)" ::: "memory");
    } else {
      asm volatile("s_waitcnt vmcnt(0)" ::: "memory");
    }
    __builtin_amdgcn_s_barrier();
    __builtin_amdgcn_sched_barrier(0);
    // (compute and stores deleted -- staging skeleton only)
    __builtin_amdgcn_sched_barrier(0);
    __builtin_amdgcn_s_barrier();
  }
}

__global__ __launch_bounds__(256) void k_probe_write(float* __restrict__ s) {
  const int blk = blockIdx.x;          // 256 blocks: inp*128 + bc
  const int bc  = blk & 127;
  const int inp = blk >> 7;
  const int tid = threadIdx.x;
  for (int t = 0; t < NSLAB; ++t) {
    float* o = s + (size_t)inp * IS + (size_t)bc * M3 + t * 256 + tid;
#pragma unroll
    for (int k = 0; k < 8; ++k) o[(size_t)k * KS] = 0.f;
  }
}

// R5 k_fwd (unchanged): persistent double-buffered gl_lds pipeline.
__global__ __launch_bounds__(512) void k_fwd(const float* __restrict__ x1,
                                             const float* __restrict__ x2,
                                             float* __restrict__ s) {
  const int blk = blockIdx.x;          // 256 blocks: inp*128 + bc
  const int bc  = blk & 127;
  const int inp = blk >> 7;
  const float* __restrict__ X = (inp ? x2 : x1) + (size_t)bc * 262144;

  __shared__ __align__(16) float buf[2][16384];   // 2 x 64 KB

  const int tid  = threadIdx.x;
  const int lane = tid & 63;
  const int wv   = tid >> 6;           // 8 waves

  auto stage = [&](int xsl, int bi) {
#pragma unroll
    for (int r = 0; r < 8; ++r) {
      const int cn = wv * 8 + r;                          // 1KB chunk 0..63
      const int gslot = cn * 64 + (lane ^ ((cn & 3) << 1));   // swizzled src
      __builtin_amdgcn_global_load_lds(
          (const __attribute__((address_space(1))) void*)(
              X + (size_t)xsl * 16384 + (size_t)gslot * 4),
          (__attribute__((address_space(3))) void*)(&buf[bi][cn * 256]),
          16, 0, 0);
    }
  };

  stage(0, 0);
  for (int t = 0; t < NSLAB; ++t) {
    if (t + 1 < NSLAB) {
      stage(t + 1, (t + 1) & 1);
      asm volatile("s_waitcnt vmcnt(8)" ::: "memory");
    } else {
      asm volatile("s_waitcnt vmcnt(0)" ::: "memory");
    }
    __builtin_amdgcn_s_barrier();
    __builtin_amdgcn_sched_barrier(0);

    if (tid < 256) {                   // waves 0-3 compute; 4-7 only stage
      const int z = tid & 15, y = tid >> 4;
      const float* bp = buf[t & 1];
      float acc[2][2][2] = {{{0.f, 0.f}, {0.f, 0.f}}, {{0.f, 0.f}, {0.f, 0.f}}};
#pragma unroll
      for (int dd = 0; dd < 4; ++dd) {
#pragma unroll
        for (int hh = 0; hh < 4; ++hh) {
          const int row = dd * 64 + 4 * y + hh;
          const int g   = row * 16 + z;                 // raw float4 slot
          const int sp  = g ^ (((g >> 6) & 3) << 1);    // swizzled LDS slot
          const float4 f = *reinterpret_cast<const float4*>(&bp[sp * 4]);
          acc[dd >> 1][hh >> 1][0] += f.x + f.y;
          acc[dd >> 1][hh >> 1][1] += f.z + f.w;
        }
      }
      const float a0 = acc[0][0][0], a1 = acc[0][0][1], a2 = acc[0][1][0], a3 = acc[0][1][1];
      const float a4 = acc[1][0][0], a5 = acc[1][0][1], a6 = acc[1][1][0], a7 = acc[1][1][1];
      const float t0 = a0 + a1, t1 = a0 - a1, t2 = a2 + a3, t3 = a2 - a3;
      const float t4 = a4 + a5, t5 = a4 - a5, t6 = a6 + a7, t7 = a6 - a7;
      const float u0 = t0 + t2, u2 = t0 - t2, u1 = t1 + t3, u3 = t1 - t3;
      const float u4 = t4 + t6, u6 = t4 - t6, u5 = t5 + t7, u7 = t5 - t7;
      float* o = s + (size_t)inp * IS + (size_t)bc * M3 + t * 256 + y * 16 + z;
      o[0 * KS] = 0.125f * (u0 + u4);
      o[4 * KS] = 0.125f * (u0 - u4);
      o[1 * KS] = 0.125f * (u1 + u5);
      o[5 * KS] = 0.125f * (u1 - u5);
      o[2 * KS] = 0.125f * (u2 + u6);
      o[6 * KS] = 0.125f * (u2 - u6);
      o[3 * KS] = 0.125f * (u3 + u7);
      o[7 * KS] = 0.125f * (u3 - u7);
    }
    __builtin_amdgcn_sched_barrier(0);
    __builtin_amdgcn_s_barrier();      // all reads of buf[t&1] done before
  }                                    // iter t+1 stages into it
}

__global__ __launch_bounds__(256) void k_mix(const float* __restrict__ W1,
                                             const float* __restrict__ W2,
                                             const float* __restrict__ s,
                                             float* __restrict__ mixed) {
  // 512 blocks: k = bid%8 (XCD-pinned so each subband's 4MiB s-slice stays in one L2)
  const int bid  = blockIdx.x;
  const int k    = bid & 7;
  const int rest = bid >> 3;       // og(4) x vblk(16)
  const int og   = rest & 3;
  const int vblk = rest >> 2;
  const int v = vblk * 256 + threadIdx.x;
  const float* pW1 = W1 + ((size_t)k * 1024 + og * 8) * M3 + v;
  const float* pW2 = W2 + ((size_t)k * 1024 + og * 8) * M3 + v;
  const float* ps  = s + (size_t)k * KS + v;
  float acc[4][8];
#pragma unroll
  for (int b = 0; b < 4; ++b)
#pragma unroll
    for (int oo = 0; oo < 8; ++oo) acc[b][oo] = 0.f;
#pragma unroll 2
  for (int i = 0; i < 32; ++i) {
    float s1b[4], s2b[4];
#pragma unroll
    for (int b = 0; b < 4; ++b) {
      s1b[b] = ps[(size_t)(b * 32 + i) * M3];
      s2b[b] = ps[(size_t)IS + (size_t)(b * 32 + i) * M3];
    }
#pragma unroll
    for (int oo = 0; oo < 8; ++oo) {
      const float w1 = pW1[(size_t)(i * 32 + oo) * M3];
      const float w2 = pW2[(size_t)(i * 32 + oo) * M3];
#pragma unroll
      for (int b = 0; b < 4; ++b) acc[b][oo] += s1b[b] * w1 + s2b[b] * w2;
    }
  }
  float* pm = mixed + (size_t)k * KS + (size_t)og * 8 * M3 + v;
#pragma unroll
  for (int b = 0; b < 4; ++b)
#pragma unroll
    for (int oo = 0; oo < 8; ++oo)
      pm[(size_t)b * (32 * M3) + (size_t)oo * M3] = acc[b][oo];
}

__global__ __launch_bounds__(256) void k_inv(const float* __restrict__ mixed,
                                             float* __restrict__ out) {
  const int tid = blockIdx.x * 256 + threadIdx.x;  // 4*32*4096 threads
  const int v = tid & 4095;
  const int o = (tid >> 12) & 31;
  const int b = tid >> 17;
  const float* pm = mixed + (size_t)(b * 32 + o) * M3 + v;
  const float m0 = pm[0 * (size_t)KS], m1 = pm[1 * (size_t)KS];
  const float m2 = pm[2 * (size_t)KS], m3 = pm[3 * (size_t)KS];
  const float m4 = pm[4 * (size_t)KS], m5 = pm[5 * (size_t)KS];
  const float m6 = pm[6 * (size_t)KS], m7 = pm[7 * (size_t)KS];
  const float t0 = m0 + m1, t1 = m0 - m1, t2 = m2 + m3, t3 = m2 - m3;
  const float t4 = m4 + m5, t5 = m4 - m5, t6 = m6 + m7, t7 = m6 - m7;
  const float u0 = t0 + t2, u2 = t0 - t2, u1 = t1 + t3, u3 = t1 - t3;
  const float u4 = t4 + t6, u6 = t4 - t6, u5 = t5 + t7, u7 = t5 - t7;
  float w[2][2][2];  // w[p][q][r], m = p*4+q*2+r, includes the 1/8
  w[0][0][0] = 0.125f * (u0 + u4);
  w[1][0][0] = 0.125f * (u0 - u4);
  w[0][0][1] = 0.125f * (u1 + u5);
  w[1][0][1] = 0.125f * (u1 - u5);
  w[0][1][0] = 0.125f * (u2 + u6);
  w[1][1][0] = 0.125f * (u2 - u6);
  w[0][1][1] = 0.125f * (u3 + u7);
  w[1][1][1] = 0.125f * (u3 - u7);
  const int z = v & 15, y = (v >> 4) & 15, x = v >> 8;
  float* base =
      out + ((((size_t)(b * 32 + o) * 64 + 4 * x) * 64 + 4 * y) * 64 + 4 * z);
#pragma unroll
  for (int dd = 0; dd < 4; ++dd) {
    const int p = dd >> 1;
#pragma unroll
    for (int hh = 0; hh < 4; ++hh) {
      const int q = hh >> 1;
      const float lo = w[p][q][0], hi = w[p][q][1];
      float4 f;
      f.x = lo; f.y = lo; f.z = hi; f.w = hi;
      *reinterpret_cast<float4*>(base + (dd * 64 + hh) * 64) = f;
    }
  }
}

extern "C" void kernel_launch(void* const* d_in, const int* in_sizes, int n_in,
                              void* d_out, int out_size, void* d_ws, size_t ws_size,
                              hipStream_t stream) {
  const float* x1 = (const float*)d_in[0];
  const float* x2 = (const float*)d_in[1];
  const float* W1 = (const float*)d_in[2];
  const float* W2 = (const float*)d_in[3];
  float* out = (float*)d_out;
  float* s     = (float*)d_ws;             // 2*IS floats = 32 MiB
  float* mixed = s + 2 * (size_t)IS;       // IS floats   = 16 MiB
  k_probe_read<<<256, 512, 0, stream>>>(x1, x2);
  k_probe_write<<<256, 256, 0, stream>>>(s);
  k_fwd<<<256, 512, 0, stream>>>(x1, x2, s);
  k_mix<<<512, 256, 0, stream>>>(W1, W2, s, mixed);
  k_inv<<<2048, 256, 0, stream>>>(mixed, out);
}

// Round 8
// 166.511 us; speedup vs baseline: 1.3468x; 1.3468x over previous
//
#include <hip/hip_runtime.h>

// WaveConv3d: B=4, C=32, D=H=W=64, LEVEL=2, m=16.
// Stage 1: s[inp][k][b][c][v16] = (1/8) * WHT3( 2x2x2 sums of 4x4x4 block )
// Stage 2: mixed[k][b][o][v] = sum_i s1*W1 + s2*W2   (per-voxel 32x32 mixing)
// Stage 3: out = (1/8) * invWHT3(mixed) broadcast to 4x4x4 blocks
//
// R7 k_fwd: multi-stream interleaved-consume loads (k_mix's proven style).
//  R6 ablation: probe_read (staging only) = 97us == full k_fwd -> the read
//  path alone was the cap. But k_mix hits ~9 TB/s delivered in the same run,
//  so 2.7 TB/s is not a machine cap. Discriminator across this session:
//  slow variants stream ONE contiguous region per thread/block (load-all-
//  then-reduce or gl_lds); fast kernels (k_mix 24 streams, k_inv 8 streams)
//  issue MANY independent per-thread address streams with each load consumed
//  immediately (compiler software-pipelines them). Copy that structure:
//  thread = (bc, voxel), 4 streams ({x1,x2} x {dd01,dd23}) x 8 float4 loads
//  interleaved into 8 float4 accumulators. No LDS, no gl_lds, default RA.

#define M3 4096        // 16*16*16 voxels
#define KS 524288      // 4*32*M3  : k-stride in s / mixed
#define IS 4194304     // 8*KS     : input-stride in s

__global__ __launch_bounds__(256) void k_fwd(const float* __restrict__ x1,
                                             const float* __restrict__ x2,
                                             float* __restrict__ s) {
  const int tid = blockIdx.x * 256 + threadIdx.x;   // 128*4096/256 = 2048 blocks
  const int v  = tid & 4095;
  const int bc = tid >> 12;          // 0..127  (b*32+c)
  const int z = v & 15, y = (v >> 4) & 15, x = v >> 8;
  const size_t base = ((((size_t)bc * 64 + 4 * x) * 64 + 4 * y) * 64 + 4 * z);
  // 4 independent address streams: {x1,x2} x {planes dd=0,1 | dd=2,3}
  const float* __restrict__ p10 = x1 + base;
  const float* __restrict__ p11 = x1 + base + 2 * 4096;
  const float* __restrict__ p20 = x2 + base;
  const float* __restrict__ p21 = x2 + base + 2 * 4096;

  float4 a1[2][2], a2[2][2];         // [p][q] float4 partial sums
#pragma unroll
  for (int p = 0; p < 2; ++p)
#pragma unroll
    for (int q = 0; q < 2; ++q) {
      a1[p][q] = make_float4(0.f, 0.f, 0.f, 0.f);
      a2[p][q] = make_float4(0.f, 0.f, 0.f, 0.f);
    }

#pragma unroll
  for (int dp = 0; dp < 2; ++dp) {     // dd within each plane-pair
#pragma unroll
    for (int hh = 0; hh < 4; ++hh) {
      const int off = (dp * 64 + hh) * 64;   // dd*4096 + hh*64
      const float4 f10 = *reinterpret_cast<const float4*>(p10 + off);
      const float4 f20 = *reinterpret_cast<const float4*>(p20 + off);
      const float4 f11 = *reinterpret_cast<const float4*>(p11 + off);
      const float4 f21 = *reinterpret_cast<const float4*>(p21 + off);
      const int q = hh >> 1;
      a1[0][q].x += f10.x; a1[0][q].y += f10.y; a1[0][q].z += f10.z; a1[0][q].w += f10.w;
      a1[1][q].x += f11.x; a1[1][q].y += f11.y; a1[1][q].z += f11.z; a1[1][q].w += f11.w;
      a2[0][q].x += f20.x; a2[0][q].y += f20.y; a2[0][q].z += f20.z; a2[0][q].w += f20.w;
      a2[1][q].x += f21.x; a2[1][q].y += f21.y; a2[1][q].z += f21.z; a2[1][q].w += f21.w;
    }
  }

#pragma unroll
  for (int inp = 0; inp < 2; ++inp) {
    float4 (*A)[2] = inp ? a2 : a1;
    const float b0 = A[0][0].x + A[0][0].y, b1 = A[0][0].z + A[0][0].w;
    const float b2 = A[0][1].x + A[0][1].y, b3 = A[0][1].z + A[0][1].w;
    const float b4 = A[1][0].x + A[1][0].y, b5 = A[1][0].z + A[1][0].w;
    const float b6 = A[1][1].x + A[1][1].y, b7 = A[1][1].z + A[1][1].w;
    const float t0 = b0 + b1, t1 = b0 - b1, t2 = b2 + b3, t3 = b2 - b3;
    const float t4 = b4 + b5, t5 = b4 - b5, t6 = b6 + b7, t7 = b6 - b7;
    const float u0 = t0 + t2, u2 = t0 - t2, u1 = t1 + t3, u3 = t1 - t3;
    const float u4 = t4 + t6, u6 = t4 - t6, u5 = t5 + t7, u7 = t5 - t7;
    float* o = s + (size_t)inp * IS + (size_t)bc * M3 + v;
    o[0 * KS] = 0.125f * (u0 + u4);
    o[4 * KS] = 0.125f * (u0 - u4);
    o[1 * KS] = 0.125f * (u1 + u5);
    o[5 * KS] = 0.125f * (u1 - u5);
    o[2 * KS] = 0.125f * (u2 + u6);
    o[6 * KS] = 0.125f * (u2 - u6);
    o[3 * KS] = 0.125f * (u3 + u7);
    o[7 * KS] = 0.125f * (u3 - u7);
  }
}

__global__ __launch_bounds__(256) void k_mix(const float* __restrict__ W1,
                                             const float* __restrict__ W2,
                                             const float* __restrict__ s,
                                             float* __restrict__ mixed) {
  // 512 blocks: k = bid%8 (XCD-pinned so each subband's 4MiB s-slice stays in one L2)
  const int bid  = blockIdx.x;
  const int k    = bid & 7;
  const int rest = bid >> 3;       // og(4) x vblk(16)
  const int og   = rest & 3;
  const int vblk = rest >> 2;
  const int v = vblk * 256 + threadIdx.x;
  const float* pW1 = W1 + ((size_t)k * 1024 + og * 8) * M3 + v;
  const float* pW2 = W2 + ((size_t)k * 1024 + og * 8) * M3 + v;
  const float* ps  = s + (size_t)k * KS + v;
  float acc[4][8];
#pragma unroll
  for (int b = 0; b < 4; ++b)
#pragma unroll
    for (int oo = 0; oo < 8; ++oo) acc[b][oo] = 0.f;
#pragma unroll 2
  for (int i = 0; i < 32; ++i) {
    float s1b[4], s2b[4];
#pragma unroll
    for (int b = 0; b < 4; ++b) {
      s1b[b] = ps[(size_t)(b * 32 + i) * M3];
      s2b[b] = ps[(size_t)IS + (size_t)(b * 32 + i) * M3];
    }
#pragma unroll
    for (int oo = 0; oo < 8; ++oo) {
      const float w1 = pW1[(size_t)(i * 32 + oo) * M3];
      const float w2 = pW2[(size_t)(i * 32 + oo) * M3];
#pragma unroll
      for (int b = 0; b < 4; ++b) acc[b][oo] += s1b[b] * w1 + s2b[b] * w2;
    }
  }
  float* pm = mixed + (size_t)k * KS + (size_t)og * 8 * M3 + v;
#pragma unroll
  for (int b = 0; b < 4; ++b)
#pragma unroll
    for (int oo = 0; oo < 8; ++oo)
      pm[(size_t)b * (32 * M3) + (size_t)oo * M3] = acc[b][oo];
}

__global__ __launch_bounds__(256) void k_inv(const float* __restrict__ mixed,
                                             float* __restrict__ out) {
  const int tid = blockIdx.x * 256 + threadIdx.x;  // 4*32*4096 threads
  const int v = tid & 4095;
  const int o = (tid >> 12) & 31;
  const int b = tid >> 17;
  const float* pm = mixed + (size_t)(b * 32 + o) * M3 + v;
  const float m0 = pm[0 * (size_t)KS], m1 = pm[1 * (size_t)KS];
  const float m2 = pm[2 * (size_t)KS], m3 = pm[3 * (size_t)KS];
  const float m4 = pm[4 * (size_t)KS], m5 = pm[5 * (size_t)KS];
  const float m6 = pm[6 * (size_t)KS], m7 = pm[7 * (size_t)KS];
  const float t0 = m0 + m1, t1 = m0 - m1, t2 = m2 + m3, t3 = m2 - m3;
  const float t4 = m4 + m5, t5 = m4 - m5, t6 = m6 + m7, t7 = m6 - m7;
  const float u0 = t0 + t2, u2 = t0 - t2, u1 = t1 + t3, u3 = t1 - t3;
  const float u4 = t4 + t6, u6 = t4 - t6, u5 = t5 + t7, u7 = t5 - t7;
  float w[2][2][2];  // w[p][q][r], m = p*4+q*2+r, includes the 1/8
  w[0][0][0] = 0.125f * (u0 + u4);
  w[1][0][0] = 0.125f * (u0 - u4);
  w[0][0][1] = 0.125f * (u1 + u5);
  w[1][0][1] = 0.125f * (u1 - u5);
  w[0][1][0] = 0.125f * (u2 + u6);
  w[1][1][0] = 0.125f * (u2 - u6);
  w[0][1][1] = 0.125f * (u3 + u7);
  w[1][1][1] = 0.125f * (u3 - u7);
  const int z = v & 15, y = (v >> 4) & 15, x = v >> 8;
  float* base =
      out + ((((size_t)(b * 32 + o) * 64 + 4 * x) * 64 + 4 * y) * 64 + 4 * z);
#pragma unroll
  for (int dd = 0; dd < 4; ++dd) {
    const int p = dd >> 1;
#pragma unroll
    for (int hh = 0; hh < 4; ++hh) {
      const int q = hh >> 1;
      const float lo = w[p][q][0], hi = w[p][q][1];
      float4 f;
      f.x = lo; f.y = lo; f.z = hi; f.w = hi;
      *reinterpret_cast<float4*>(base + (dd * 64 + hh) * 64) = f;
    }
  }
}

extern "C" void kernel_launch(void* const* d_in, const int* in_sizes, int n_in,
                              void* d_out, int out_size, void* d_ws, size_t ws_size,
                              hipStream_t stream) {
  const float* x1 = (const float*)d_in[0];
  const float* x2 = (const float*)d_in[1];
  const float* W1 = (const float*)d_in[2];
  const float* W2 = (const float*)d_in[3];
  float* out = (float*)d_out;
  float* s     = (float*)d_ws;             // 2*IS floats = 32 MiB
  float* mixed = s + 2 * (size_t)IS;       // IS floats   = 16 MiB
  k_fwd<<<2048, 256, 0, stream>>>(x1, x2, s);
  k_mix<<<512, 256, 0, stream>>>(W1, W2, s, mixed);
  k_inv<<<2048, 256, 0, stream>>>(mixed, out);
}